// Round 9
// baseline (842.255 us; speedup 1.0000x reference)
//
#include <hip/hip_runtime.h>
#include <hip/hip_bf16.h>
#include <stdint.h>

typedef __attribute__((ext_vector_type(8))) short s16x8;
typedef __attribute__((ext_vector_type(4))) float f32x4;

#define D_DIM 2048
#define V_DIM 32768
#define M_DIM 4096
#define N_SEQ 2048
#define K_TOP 64
#define NSLOT 512   // 128 v-tiles * 4 wc
#define EBCAP 512   // entries per 256x256 tile (avg ~130)

// ---------- helpers ----------
static __device__ __forceinline__ float bf2f(unsigned short u) {
  union { unsigned int i; float f; } v; v.i = ((unsigned int)u) << 16; return v.f;
}
static __device__ __forceinline__ unsigned int pack2_bf16(float lo, float hi) {
  unsigned int ul = __float_as_uint(lo), uh = __float_as_uint(hi);
  ul = (ul + 0x7FFFu + ((ul >> 16) & 1u)) >> 16;        // RNE
  uh = (uh + 0x7FFFu + ((uh >> 16) & 1u)) >> 16;
  return ul | (uh << 16);
}
typedef __attribute__((address_space(3))) unsigned int lds_u32_t;
typedef const __attribute__((address_space(1))) unsigned int glb_u32_t;
static __device__ __forceinline__ void gload16(const void* g, void* l) {
  __builtin_amdgcn_global_load_lds((glb_u32_t*)g, (lds_u32_t*)l, 16, 0, 0);
}

// ---------- cast f32 -> bf16 (both tensors, one launch) ----------
__global__ void cast_bf16_kernel(const float4* __restrict__ inA, uint4* __restrict__ outA, int nA8,
                                 const float4* __restrict__ inB, uint4* __restrict__ outB, int nB8) {
  int i = blockIdx.x * blockDim.x + threadIdx.x;
  int stride = gridDim.x * blockDim.x;
  int tot = nA8 + nB8;
  for (; i < tot; i += stride) {
    const float4* in = (i < nA8) ? inA : inB;
    uint4* out = (i < nA8) ? outA : outB;
    int j = (i < nA8) ? i : i - nA8;
    float4 a = in[2 * j], b = in[2 * j + 1];
    uint4 r;
    r.x = pack2_bf16(a.x, a.y);
    r.y = pack2_bf16(a.z, a.w);
    r.z = pack2_bf16(b.x, b.y);
    r.w = pack2_bf16(b.z, b.w);
    out[j] = r;
  }
}

// ---------- binning: (m, id) -> per-(mt,vt)-tile entry lists ----------
__global__ __launch_bounds__(256) void bin_kernel(
    const int* __restrict__ tids, const int* __restrict__ tlab,
    unsigned int* __restrict__ cnt, unsigned int* __restrict__ ebuf) {
  int idx = blockIdx.x * 256 + threadIdx.x;
  if (idx >= M_DIM * (K_TOP + 1)) return;
  int m = idx / (K_TOP + 1), k = idx - m * (K_TOP + 1);
  int id;
  if (k < K_TOP) id = tids[m * K_TOP + k];
  else {
    int n = m & (N_SEQ - 1);
    if (n == N_SEQ - 1) return;   // no gold for last position
    id = tlab[m + 1];
  }
  int tile = ((m >> 8) << 7) + (id >> 8);   // mt*128 + vt
  unsigned int pos = atomicAdd(&cnt[tile], 1u);
  if (pos < EBCAP)
    ebuf[tile * EBCAP + pos] =
        ((unsigned int)k << 16) | ((unsigned int)(m & 255) << 8) | (unsigned int)(id & 255);
}

// ---------- 256x256 GEMM, 16x16x32 MFMA, reads-issued-before-MFMA ----------
// 8 waves (2M x 4N), BK=64, 128KB LDS dbuf, halves pos0/1=B, pos2/3=A.
// Granule swizzle g ^= row&7 (pre-applied on global src) -> ~0 conflicts.
// Segment = {BAR; stage; ISSUE next-window reads; MFMA burst consuming last
// window's reads}. Read service hides under the MFMA issue burst; consuming
// MFMA is 1 barrier later (compiler emits counted lgkmcnt).
//  s1: BAR; stage (T+2)p0; read A mi2,3 -> aqn;        MFMA mi0-1 (aq)
//  s2: BAR; stage (T+2)p1; read A mi4,5 -> aq;         MFMA mi2-3 (aqn)
//  s3: BAR;                read A mi6,7 -> aqn; VMC(4);MFMA mi4-5 (aq)
//  s4: BAR; stage (T+2)p2,p3; read B(T+1)+A(T+1)mi0,1; MFMA mi6-7 (aqn)
// Liveness unchanged from r8; VMC(4) at s3 guarantees tile T+1 landed.

#define BAR do { __builtin_amdgcn_s_barrier(); asm volatile("" ::: "memory"); } while (0)
#define VMC(N) asm volatile("s_waitcnt vmcnt(" #N ")" ::: "memory")
#define PRIO1 __builtin_amdgcn_s_setprio(1)
#define PRIO0 __builtin_amdgcn_s_setprio(0)

#define LDFRAG(BASE, R, G) \
  (*(const s16x8*)((BASE) + (R) * 128 + ((((G)) ^ ((R) & 7)) << 4)))
#define LDA(BASE, MI, KS) LDFRAG(BASE, (MI) * 16 + fr, (KS) * 4 + kqg)
#define LDB(BASE, NI, KS) LDFRAG(BASE, brow + (NI) * 16 + fr, (KS) * 4 + kqg)

#define STAGE(H) do { \
  int tt_ = (H) >> 2, pos_ = (H) & 3; \
  char* dst_ = ldst + ((tt_ & 1) << 16) + (pos_ << 14); \
  const unsigned short* src_ = ((pos_ & 2) ? aptr : bptr) \
      + ((pos_ & 1) ? (size_t)128 * D_DIM : (size_t)0) + (size_t)tt_ * 64; \
  gload16(src_, dst_); \
  gload16(src_ + (size_t)64 * D_DIM, dst_ + 8192); \
} while (0)

// dependent reuse distance = 8 MFMAs (k0 sweep then k1 sweep)
#define MFMA_Q(M0, U) do { \
  _Pragma("unroll") \
  for (int ni = 0; ni < 4; ++ni) \
    acc[M0][ni] = __builtin_amdgcn_mfma_f32_16x16x32_bf16(U[0][0], bfrag[ni][0], acc[M0][ni], 0, 0, 0); \
  _Pragma("unroll") \
  for (int ni = 0; ni < 4; ++ni) \
    acc[(M0) + 1][ni] = __builtin_amdgcn_mfma_f32_16x16x32_bf16(U[1][0], bfrag[ni][0], acc[(M0) + 1][ni], 0, 0, 0); \
  _Pragma("unroll") \
  for (int ni = 0; ni < 4; ++ni) \
    acc[M0][ni] = __builtin_amdgcn_mfma_f32_16x16x32_bf16(U[0][1], bfrag[ni][1], acc[M0][ni], 0, 0, 0); \
  _Pragma("unroll") \
  for (int ni = 0; ni < 4; ++ni) \
    acc[(M0) + 1][ni] = __builtin_amdgcn_mfma_f32_16x16x32_bf16(U[1][1], bfrag[ni][1], acc[(M0) + 1][ni], 0, 0, 0); \
} while (0)

// Entering invariant: bfrag = B(T), aq = A-q0(T) (read in s4 of T-1 / prologue).
#define TILE1B(T, DOST, NVM, DONEXT) do { \
  char* curA_ = ldsAroot + (((T) & 1) << 16); \
  char* nxtA_ = ldsAroot + ((((T) + 1) & 1) << 16); \
  char* nxtB_ = ldsBroot + ((((T) + 1) & 1) << 16); \
  /* s1 */ \
  BAR; \
  if (DOST) STAGE(4 * (T) + 8); \
  aqn[0][0] = LDA(curA_, 2, 0); aqn[0][1] = LDA(curA_, 2, 1); \
  aqn[1][0] = LDA(curA_, 3, 0); aqn[1][1] = LDA(curA_, 3, 1); \
  PRIO1; MFMA_Q(0, aq); PRIO0; \
  /* s2 */ \
  BAR; \
  if (DOST) STAGE(4 * (T) + 9); \
  aq[0][0] = LDA(curA_, 4, 0); aq[0][1] = LDA(curA_, 4, 1); \
  aq[1][0] = LDA(curA_, 5, 0); aq[1][1] = LDA(curA_, 5, 1); \
  PRIO1; MFMA_Q(2, aqn); PRIO0; \
  /* s3 */ \
  BAR; \
  aqn[0][0] = LDA(curA_, 6, 0); aqn[0][1] = LDA(curA_, 6, 1); \
  aqn[1][0] = LDA(curA_, 7, 0); aqn[1][1] = LDA(curA_, 7, 1); \
  if ((NVM) == 4) { VMC(4); } else if ((NVM) == 0) { VMC(0); } \
  PRIO1; MFMA_Q(4, aq); PRIO0; \
  /* s4 */ \
  BAR; \
  if (DOST) { STAGE(4 * (T) + 10); STAGE(4 * (T) + 11); } \
  if (DONEXT) { \
    _Pragma("unroll") \
    for (int ni = 0; ni < 4; ++ni) { \
      bfragN[ni][0] = LDB(nxtB_, ni, 0); bfragN[ni][1] = LDB(nxtB_, ni, 1); } \
    aq[0][0] = LDA(nxtA_, 0, 0); aq[0][1] = LDA(nxtA_, 0, 1); \
    aq[1][0] = LDA(nxtA_, 1, 0); aq[1][1] = LDA(nxtA_, 1, 1); \
  } \
  PRIO1; MFMA_Q(6, aqn); PRIO0; \
  _Pragma("unroll") \
  for (int ni = 0; ni < 4; ++ni) { \
    bfrag[ni][0] = bfragN[ni][0]; bfrag[ni][1] = bfragN[ni][1]; } \
} while (0)

__global__ __launch_bounds__(512, 2) void gemm_lse_kernel(
    const unsigned short* __restrict__ xbf,   // [M_DIM][D_DIM]
    const unsigned short* __restrict__ wbf,   // [V_DIM][D_DIM]
    float* __restrict__ pMax,                 // [M_DIM][NSLOT]
    float* __restrict__ pSum,
    const unsigned int* __restrict__ bcnt,    // [2048]
    const unsigned int* __restrict__ ebuf,    // [2048][EBCAP]
    float* __restrict__ gout) {               // [M_DIM][K_TOP+1]
  __shared__ __align__(16) char lds[131072];

  // Locality mapping (round-5): round of 256 blocks = 16mt x 16vt square;
  // each XCD pinned to 2 vt columns.
  const int bid0 = blockIdx.x;
  const int mt = (bid0 >> 4) & 15;
  const int vt = ((bid0 >> 8) << 4) | (bid0 & 15);
  const int tid = threadIdx.x, lane = tid & 63, w = tid >> 6;
  const int wr = w >> 2, wc = w & 3;
  const int fr = lane & 15, kqg = lane >> 4;
  const int brow = (wc & 1) * 64;

  const int gcol = (((tid & 7) ^ ((tid >> 3) & 7)) << 3);
  const unsigned short* aptr = xbf + (size_t)(mt * 256 + (tid >> 3)) * D_DIM + gcol;
  const unsigned short* bptr = wbf + (size_t)(vt * 256 + (tid >> 3)) * D_DIM + gcol;
  char* ldst = lds + tid * 16;

  char* ldsAroot = lds + ((2 + wr) << 14);
  char* ldsBroot = lds + ((wc >> 1) << 14);

  f32x4 acc[8][4];
#pragma unroll
  for (int i = 0; i < 8; i++)
#pragma unroll
    for (int j = 0; j < 4; j++) acc[i][j] = (f32x4){0.f, 0.f, 0.f, 0.f};

  s16x8 bfrag[4][2], bfragN[4][2], aq[2][2], aqn[2][2];

  // prologue: stage tiles 0 and 1 fully (halves 0..7), drain, pre-read tile0
  STAGE(0); STAGE(1); STAGE(2); STAGE(3);
  VMC(4);
  STAGE(4); STAGE(5); STAGE(6); STAGE(7);
  VMC(0);
  BAR;
#pragma unroll
  for (int ni = 0; ni < 4; ++ni) {
    bfrag[ni][0] = LDB(ldsBroot, ni, 0); bfrag[ni][1] = LDB(ldsBroot, ni, 1);
  }
  aq[0][0] = LDA(ldsAroot, 0, 0); aq[0][1] = LDA(ldsAroot, 0, 1);
  aq[1][0] = LDA(ldsAroot, 1, 0); aq[1][1] = LDA(ldsAroot, 1, 1);

  // main loop: tiles 0..29 (stage T+2), tail tiles 30, 31
  for (int it = 0; it < 15; ++it) {
    TILE1B(2 * it, 1, 4, 1);
    TILE1B(2 * it + 1, 1, 4, 1);
  }
  TILE1B(30, 0, 0, 1);
  TILE1B(31, 0, 99, 0);

  // ---- epilogue A: per-row (max, sumexp) over this wave's 64-col slice ----
  const int slot = vt * 4 + wc;
#pragma unroll
  for (int mi = 0; mi < 8; mi++) {
#pragma unroll
    for (int j = 0; j < 4; j++) {
      const int row = mt * 256 + wr * 128 + mi * 16 + kqg * 4 + j;
      float v0 = acc[mi][0][j], v1 = acc[mi][1][j];
      float v2 = acc[mi][2][j], v3 = acc[mi][3][j];
      float mx = fmaxf(fmaxf(v0, v1), fmaxf(v2, v3));
      for (int s = 1; s < 16; s <<= 1) mx = fmaxf(mx, __shfl_xor(mx, s));
      float sm = __expf(v0 - mx) + __expf(v1 - mx) +
                 __expf(v2 - mx) + __expf(v3 - mx);
      for (int s = 1; s < 16; s <<= 1) sm += __shfl_xor(sm, s);
      if (fr == 0) {
        pMax[row * NSLOT + slot] = mx;
        pSum[row * NSLOT + slot] = sm;
      }
    }
  }

  // ---- epilogue B: fused gather of requested logits via LDS round-trip ----
  // col swizzle c ^= ((r>>2)&1)<<4 spreads the 4 kqg-rows across banks (2-way = free)
  const int tile = (mt << 7) + vt;
  unsigned int cn = bcnt[tile];
  if (cn > EBCAP) cn = EBCAP;
  const unsigned int* elist = ebuf + tile * EBCAP;
  float* ldsf = (float*)lds;

  __syncthreads();
#pragma unroll
  for (int half = 0; half < 2; ++half) {
    if (wr == half) {
#pragma unroll
      for (int mi = 0; mi < 8; mi++) {
        const int r0 = mi * 16 + kqg * 4;
        const int cs = (kqg & 1) << 4;
#pragma unroll
        for (int ni = 0; ni < 4; ni++) {
          const int c0 = (wc * 64 + ni * 16 + fr) ^ cs;
#pragma unroll
          for (int j = 0; j < 4; j++)
            ldsf[(r0 + j) * 256 + c0] = acc[mi][ni][j];
        }
      }
    }
    __syncthreads();
    for (unsigned int e = tid; e < cn; e += 512) {
      unsigned int u = elist[e];
      int r = (u >> 8) & 255;
      if ((r >> 7) == half) {
        int c = u & 255, k = u >> 16;
        int rl = r & 127;
        gout[(mt * 256 + r) * (K_TOP + 1) + k] = ldsf[rl * 256 + (c ^ (((rl >> 2) & 1) << 4))];
      }
    }
    __syncthreads();
  }
}

// ---------- final: lse merge + CE + KD, atomic into scalar ----------
__global__ __launch_bounds__(256) void reduce_kernel(
    const float* __restrict__ pMax, const float* __restrict__ pSum,
    const float* __restrict__ gout, const float* __restrict__ t_lp,
    const int* __restrict__ t_mask, float* __restrict__ out) {
  const int tid = threadIdx.x, lane = tid & 63, w = tid >> 6;
  const int m = blockIdx.x * 4 + w;

  float msl[8], ssl[8];
  float M = -1e30f;
#pragma unroll
  for (int j = 0; j < 8; j++) {
    msl[j] = pMax[m * NSLOT + lane + j * 64];
    ssl[j] = pSum[m * NSLOT + lane + j * 64];
    M = fmaxf(M, msl[j]);
  }
  for (int s = 1; s < 64; s <<= 1) M = fmaxf(M, __shfl_xor(M, s));
  float S = 0.f;
#pragma unroll
  for (int j = 0; j < 8; j++) S += ssl[j] * __expf(msl[j] - M);
  for (int s = 1; s < 64; s <<= 1) S += __shfl_xor(S, s);
  const float lse = M + logf(S);

  const int n = m & (N_SEQ - 1);
  float ce = 0.f;
  if (n < N_SEQ - 1) ce = lse - gout[m * (K_TOP + 1) + K_TOP];

  const float g = gout[m * (K_TOP + 1) + lane];
  float gM = g;
  for (int s = 1; s < 64; s <<= 1) gM = fmaxf(gM, __shfl_xor(gM, s));
  float gE = __expf(g - gM);
  float gS = gE;
  for (int s = 1; s < 64; s <<= 1) gS += __shfl_xor(gS, s);
  const float lseK = gM + logf(gS);

  const float tl = t_lp[m * K_TOP + lane];
  const int mk = t_mask[m * K_TOP + lane];
  float kd = mk ? __expf(tl) * (tl - (g - lseK)) : 0.f;
  for (int s = 1; s < 64; s <<= 1) kd += __shfl_xor(kd, s);

  if (lane == 0) atomicAdd(out, 0.5f * kd + 0.5f * ce);
}

// ---------- launch ----------
extern "C" void kernel_launch(void* const* d_in, const int* in_sizes, int n_in,
                              void* d_out, int out_size, void* d_ws, size_t ws_size,
                              hipStream_t stream) {
  const float* x   = (const float*)d_in[0];   // [2,2048,2048]
  const float* Wm  = (const float*)d_in[1];   // [32768,2048]
  const int* tids  = (const int*)d_in[2];     // [2,2048,64]
  const float* tlp = (const float*)d_in[3];   // [2,2048,64]
  const int* tmask = (const int*)d_in[4];     // [2,2048,64]
  const int* tlab  = (const int*)d_in[5];     // [2,2048]
  float* out = (float*)d_out;

  char* ws = (char*)d_ws;
  unsigned short* wbf = (unsigned short*)ws;                                 // 128 MB
  unsigned short* xbf = (unsigned short*)(ws + (size_t)V_DIM * D_DIM * 2);   // 16 MB
  char* p = ws + (size_t)V_DIM * D_DIM * 2 + (size_t)M_DIM * D_DIM * 2;
  float* pMax = (float*)p;                       p += (size_t)M_DIM * NSLOT * 4;
  float* pSum = (float*)p;                       p += (size_t)M_DIM * NSLOT * 4;
  float* gout = (float*)p;                       p += (size_t)M_DIM * (K_TOP + 1) * 4;
  unsigned int* bcnt = (unsigned int*)p;         p += 2048 * 4;
  unsigned int* ebuf = (unsigned int*)p;         p += (size_t)2048 * EBCAP * 4;

  hipMemsetAsync(d_out, 0, sizeof(float), stream);
  hipMemsetAsync(bcnt, 0, 2048 * 4, stream);

  bin_kernel<<<(M_DIM * (K_TOP + 1) + 255) / 256, 256, 0, stream>>>(
      tids, tlab, bcnt, ebuf);

  cast_bf16_kernel<<<8192, 256, 0, stream>>>(
      (const float4*)Wm, (uint4*)wbf, (V_DIM * D_DIM) / 8,
      (const float4*)x, (uint4*)xbf, (M_DIM * D_DIM) / 8);

  gemm_lse_kernel<<<(M_DIM / 256) * (V_DIM / 256), 512, 0, stream>>>(
      xbf, wbf, pMax, pSum, bcnt, ebuf, gout);

  reduce_kernel<<<M_DIM / 4, 256, 0, stream>>>(pMax, pSum, gout, tlp, tmask, out);
}

// Round 10
// 570.234 us; speedup vs baseline: 1.4770x; 1.4770x over previous
//
#include <hip/hip_runtime.h>
#include <hip/hip_bf16.h>
#include <stdint.h>

typedef __attribute__((ext_vector_type(4))) float f32x4;

#define D_DIM 2048
#define V_DIM 32768
#define M_DIM 4096
#define N_SEQ 2048
#define K_TOP 64
#define NSLOT 512   // 128 v-tiles * 4 wc
#define EBCAP 512   // entries per 256x256 tile (avg ~130)
#define WSCALE 64.0f
#define IWSCALE 0.015625f

// ---------- helpers ----------
static __device__ __forceinline__ unsigned int f32_to_e4m3(float x) {
  float ax = fminf(fabsf(x), 448.0f);
  unsigned int s = (__float_as_uint(x) >> 31) << 7;
  if (ax >= 0.015625f) {
    unsigned int m = __float_as_uint(ax);
    unsigned int keep = m >> 20;
    unsigned int rb = (m >> 19) & 1u, st = (m & 0x7FFFFu) != 0u;
    keep += rb & (st | (keep & 1u));
    int v = (int)keep - (120 << 3);
    if (v > 0x7E) v = 0x7E;
    return s | (unsigned int)v;
  } else {
    int m = __float2int_rn(ax * 512.0f);
    return s | (unsigned int)m;
  }
}

typedef __attribute__((address_space(3))) unsigned int lds_u32_t;
typedef const __attribute__((address_space(1))) unsigned int glb_u32_t;
static __device__ __forceinline__ void gload16(const void* g, void* l) {
  __builtin_amdgcn_global_load_lds((glb_u32_t*)g, (lds_u32_t*)l, 16, 0, 0);
}

// ---------- cast f32 -> fp8 e4m3 (W scaled x64, x unscaled) ----------
__global__ void cast_fp8_kernel(const float4* __restrict__ inA, uint2* __restrict__ outA, int nA8,
                                const float4* __restrict__ inB, uint2* __restrict__ outB, int nB8) {
  int i = blockIdx.x * blockDim.x + threadIdx.x;
  int stride = gridDim.x * blockDim.x;
  int tot = nA8 + nB8;
  for (; i < tot; i += stride) {
    const float4* in = (i < nA8) ? inA : inB;
    uint2* out = (i < nA8) ? outA : outB;
    float sc = (i < nA8) ? WSCALE : 1.0f;
    int j = (i < nA8) ? i : i - nA8;
    float4 a = in[2 * j], b = in[2 * j + 1];
    uint2 r;
    r.x = f32_to_e4m3(a.x * sc) | (f32_to_e4m3(a.y * sc) << 8) |
          (f32_to_e4m3(a.z * sc) << 16) | (f32_to_e4m3(a.w * sc) << 24);
    r.y = f32_to_e4m3(b.x * sc) | (f32_to_e4m3(b.y * sc) << 8) |
          (f32_to_e4m3(b.z * sc) << 16) | (f32_to_e4m3(b.w * sc) << 24);
    out[j] = r;
  }
}

// ---------- binning: (m, id) -> per-(mt,vt)-tile entry lists ----------
__global__ __launch_bounds__(256) void bin_kernel(
    const int* __restrict__ tids, const int* __restrict__ tlab,
    unsigned int* __restrict__ cnt, unsigned int* __restrict__ ebuf) {
  int idx = blockIdx.x * 256 + threadIdx.x;
  if (idx >= M_DIM * (K_TOP + 1)) return;
  int m = idx / (K_TOP + 1), k = idx - m * (K_TOP + 1);
  int id;
  if (k < K_TOP) id = tids[m * K_TOP + k];
  else {
    int n = m & (N_SEQ - 1);
    if (n == N_SEQ - 1) return;   // no gold for last position
    id = tlab[m + 1];
  }
  int tile = ((m >> 8) << 7) + (id >> 8);   // mt*128 + vt
  unsigned int pos = atomicAdd(&cnt[tile], 1u);
  if (pos < EBCAP)
    ebuf[tile * EBCAP + pos] =
        ((unsigned int)k << 16) | ((unsigned int)(m & 255) << 8) | (unsigned int)(id & 255);
}

// ---------- 256x256 GEMM, fp8 16x16x32 MFMA, r8 segment schedule ----------
// 8 waves (2M x 4N), BK=64 (64 B/row fp8), 64KB LDS dbuf (halves 8KB:
// pos0/1 = B rows 0-127/128-255, pos2/3 = A). Granule swizzle (4 granules):
// g' = g ^ (r&3) ^ ((r>>2)&3), inverse pre-applied on global src. 2-way max.
// Frags are 8B (ds_read_b64-class); MFMA operands i64. acc descaled x1/64
// in epilogues (W pre-scaled x64 into fp8 to avoid subnormals).

#define BAR do { __builtin_amdgcn_s_barrier(); asm volatile("" ::: "memory"); } while (0)
#define VMC(N) asm volatile("s_waitcnt vmcnt(" #N ")" ::: "memory")
#define PRIO1 __builtin_amdgcn_s_setprio(1)
#define PRIO0 __builtin_amdgcn_s_setprio(0)

#define LD8(BASE, R, KS) \
  (*(const long*)((BASE) + (R) * 64 + \
     (((2 * (KS) + (kqg >> 1)) ^ ((R) & 3) ^ (((R) >> 2) & 3)) << 4) + ((kqg & 1) << 3)))
#define LDA8(BASE, MI, KS) LD8(BASE, (MI) * 16 + fr, KS)
#define LDB8(BASE, NI, KS) LD8(BASE, brow + (NI) * 16 + fr, KS)

#define STAGE(H) do { \
  int tt_ = (H) >> 2, pos_ = (H) & 3; \
  char* dst_ = ldst + ((tt_ & 1) << 15) + (pos_ << 13); \
  const unsigned char* src_ = ((pos_ & 2) ? aptr : bptr) \
      + ((pos_ & 1) ? (size_t)128 * D_DIM : (size_t)0) + (size_t)tt_ * 64; \
  gload16(src_, dst_); \
} while (0)

// dependent reuse distance = 8 MFMAs (k0 sweep then k1 sweep)
#define MFMA_Q(M0, U) do { \
  _Pragma("unroll") \
  for (int ni = 0; ni < 4; ++ni) \
    acc[M0][ni] = __builtin_amdgcn_mfma_f32_16x16x32_fp8_fp8(U[0][0], bfrag[ni][0], acc[M0][ni], 0, 0, 0); \
  _Pragma("unroll") \
  for (int ni = 0; ni < 4; ++ni) \
    acc[(M0) + 1][ni] = __builtin_amdgcn_mfma_f32_16x16x32_fp8_fp8(U[1][0], bfrag[ni][0], acc[(M0) + 1][ni], 0, 0, 0); \
  _Pragma("unroll") \
  for (int ni = 0; ni < 4; ++ni) \
    acc[M0][ni] = __builtin_amdgcn_mfma_f32_16x16x32_fp8_fp8(U[0][1], bfrag[ni][1], acc[M0][ni], 0, 0, 0); \
  _Pragma("unroll") \
  for (int ni = 0; ni < 4; ++ni) \
    acc[(M0) + 1][ni] = __builtin_amdgcn_mfma_f32_16x16x32_fp8_fp8(U[1][1], bfrag[ni][1], acc[(M0) + 1][ni], 0, 0, 0); \
} while (0)

// Entering invariant: bfrag = B(T), aq = A mi0,1 of T (read in s4 of T-1 / prologue).
#define TILE1B(T, DOST, NVM, DONEXT) do { \
  char* curA_ = ldsAroot + (((T) & 1) << 15); \
  char* nxtA_ = ldsAroot + ((((T) + 1) & 1) << 15); \
  char* nxtB_ = ldsBroot + ((((T) + 1) & 1) << 15); \
  /* s1 */ \
  BAR; \
  if (DOST) STAGE(4 * (T) + 8); \
  PRIO1; MFMA_Q(0, aq); PRIO0; \
  aqn[0][0] = LDA8(curA_, 2, 0); aqn[0][1] = LDA8(curA_, 2, 1); \
  aqn[1][0] = LDA8(curA_, 3, 0); aqn[1][1] = LDA8(curA_, 3, 1); \
  /* s2 */ \
  BAR; \
  if (DOST) STAGE(4 * (T) + 9); \
  PRIO1; MFMA_Q(2, aqn); PRIO0; \
  aq[0][0] = LDA8(curA_, 4, 0); aq[0][1] = LDA8(curA_, 4, 1); \
  aq[1][0] = LDA8(curA_, 5, 0); aq[1][1] = LDA8(curA_, 5, 1); \
  /* s3 */ \
  BAR; \
  PRIO1; MFMA_Q(4, aq); PRIO0; \
  aqn[0][0] = LDA8(curA_, 6, 0); aqn[0][1] = LDA8(curA_, 6, 1); \
  aqn[1][0] = LDA8(curA_, 7, 0); aqn[1][1] = LDA8(curA_, 7, 1); \
  if ((NVM) == 2) { VMC(2); } else if ((NVM) == 0) { VMC(0); } \
  /* s4 */ \
  BAR; \
  if (DOST) { STAGE(4 * (T) + 10); STAGE(4 * (T) + 11); } \
  PRIO1; MFMA_Q(6, aqn); PRIO0; \
  if (DONEXT) { \
    _Pragma("unroll") \
    for (int ni = 0; ni < 4; ++ni) { \
      bfrag[ni][0] = LDB8(nxtB_, ni, 0); bfrag[ni][1] = LDB8(nxtB_, ni, 1); } \
    aq[0][0] = LDA8(nxtA_, 0, 0); aq[0][1] = LDA8(nxtA_, 0, 1); \
    aq[1][0] = LDA8(nxtA_, 1, 0); aq[1][1] = LDA8(nxtA_, 1, 1); \
  } \
} while (0)

__global__ __launch_bounds__(512, 2) void gemm_lse_kernel(
    const unsigned char* __restrict__ x8,     // [M_DIM][D_DIM] fp8
    const unsigned char* __restrict__ w8,     // [V_DIM][D_DIM] fp8 (x64)
    float* __restrict__ pMax,                 // [M_DIM][NSLOT]
    float* __restrict__ pSum,
    const unsigned int* __restrict__ bcnt,    // [2048]
    const unsigned int* __restrict__ ebuf,    // [2048][EBCAP]
    float* __restrict__ gout) {               // [M_DIM][K_TOP+1]
  __shared__ __align__(16) char lds[131072];  // GEMM uses first 64KB; epilogue all

  // Locality mapping (round-5): round of 256 blocks = 16mt x 16vt square;
  // each XCD pinned to 2 vt columns.
  const int bid0 = blockIdx.x;
  const int mt = (bid0 >> 4) & 15;
  const int vt = ((bid0 >> 8) << 4) | (bid0 & 15);
  const int tid = threadIdx.x, lane = tid & 63, w = tid >> 6;
  const int wr = w >> 2, wc = w & 3;
  const int fr = lane & 15, kqg = lane >> 4;
  const int brow = (wc & 1) * 64;

  // staging: thread t -> row t>>2 (pos&1 adds 128), granule t&3; src pre-swizzled
  const int gcol = (((tid & 3) ^ ((tid >> 2) & 3) ^ ((tid >> 4) & 3)) << 4);
  const unsigned char* aptr = x8 + (size_t)(mt * 256 + (tid >> 2)) * D_DIM + gcol;
  const unsigned char* bptr = w8 + (size_t)(vt * 256 + (tid >> 2)) * D_DIM + gcol;
  char* ldst = lds + tid * 16;

  char* ldsAroot = lds + ((2 + wr) << 13);
  char* ldsBroot = lds + ((wc >> 1) << 13);

  f32x4 acc[8][4];
#pragma unroll
  for (int i = 0; i < 8; i++)
#pragma unroll
    for (int j = 0; j < 4; j++) acc[i][j] = (f32x4){0.f, 0.f, 0.f, 0.f};

  long bfrag[4][2], aq[2][2], aqn[2][2];

  // prologue: stage tiles 0 and 1 fully (halves 0..7), drain, pre-read tile0
  STAGE(0); STAGE(1); STAGE(2); STAGE(3);
  STAGE(4); STAGE(5); STAGE(6); STAGE(7);
  VMC(0);
  BAR;
#pragma unroll
  for (int ni = 0; ni < 4; ++ni) {
    bfrag[ni][0] = LDB8(ldsBroot, ni, 0); bfrag[ni][1] = LDB8(ldsBroot, ni, 1);
  }
  aq[0][0] = LDA8(ldsAroot, 0, 0); aq[0][1] = LDA8(ldsAroot, 0, 1);
  aq[1][0] = LDA8(ldsAroot, 1, 0); aq[1][1] = LDA8(ldsAroot, 1, 1);

  // main loop: tiles 0..29 (stage T+2), tail tiles 30, 31
  for (int it = 0; it < 15; ++it) {
    TILE1B(2 * it, 1, 2, 1);
    TILE1B(2 * it + 1, 1, 2, 1);
  }
  TILE1B(30, 0, 0, 1);
  TILE1B(31, 0, 99, 0);

  // ---- epilogue A: per-row (max, sumexp); descale acc by 1/64 ----
  const int slot = vt * 4 + wc;
#pragma unroll
  for (int mi = 0; mi < 8; mi++) {
#pragma unroll
    for (int j = 0; j < 4; j++) {
      const int row = mt * 256 + wr * 128 + mi * 16 + kqg * 4 + j;
      float v0 = acc[mi][0][j] * IWSCALE, v1 = acc[mi][1][j] * IWSCALE;
      float v2 = acc[mi][2][j] * IWSCALE, v3 = acc[mi][3][j] * IWSCALE;
      float mx = fmaxf(fmaxf(v0, v1), fmaxf(v2, v3));
      for (int s = 1; s < 16; s <<= 1) mx = fmaxf(mx, __shfl_xor(mx, s));
      float sm = __expf(v0 - mx) + __expf(v1 - mx) +
                 __expf(v2 - mx) + __expf(v3 - mx);
      for (int s = 1; s < 16; s <<= 1) sm += __shfl_xor(sm, s);
      if (fr == 0) {
        pMax[row * NSLOT + slot] = mx;
        pSum[row * NSLOT + slot] = sm;
      }
    }
  }

  // ---- epilogue B: fused gather of requested logits via LDS round-trip ----
  const int tile = (mt << 7) + vt;
  unsigned int cn = bcnt[tile];
  if (cn > EBCAP) cn = EBCAP;
  const unsigned int* elist = ebuf + tile * EBCAP;
  float* ldsf = (float*)lds;

  __syncthreads();
#pragma unroll
  for (int half = 0; half < 2; ++half) {
    if (wr == half) {
#pragma unroll
      for (int mi = 0; mi < 8; mi++) {
        const int r0 = mi * 16 + kqg * 4;
        const int cs = (kqg & 1) << 4;
#pragma unroll
        for (int ni = 0; ni < 4; ni++) {
          const int c0 = (wc * 64 + ni * 16 + fr) ^ cs;
#pragma unroll
          for (int j = 0; j < 4; j++)
            ldsf[(r0 + j) * 256 + c0] = acc[mi][ni][j] * IWSCALE;
        }
      }
    }
    __syncthreads();
    for (unsigned int e = tid; e < cn; e += 512) {
      unsigned int u = elist[e];
      int r = (u >> 8) & 255;
      if ((r >> 7) == half) {
        int c = u & 255, k = u >> 16;
        int rl = r & 127;
        gout[(mt * 256 + r) * (K_TOP + 1) + k] = ldsf[rl * 256 + (c ^ (((rl >> 2) & 1) << 4))];
      }
    }
    __syncthreads();
  }
}

// ---------- final: lse merge + CE + KD, atomic into scalar ----------
__global__ __launch_bounds__(256) void reduce_kernel(
    const float* __restrict__ pMax, const float* __restrict__ pSum,
    const float* __restrict__ gout, const float* __restrict__ t_lp,
    const int* __restrict__ t_mask, float* __restrict__ out) {
  const int tid = threadIdx.x, lane = tid & 63, w = tid >> 6;
  const int m = blockIdx.x * 4 + w;

  float msl[8], ssl[8];
  float M = -1e30f;
#pragma unroll
  for (int j = 0; j < 8; j++) {
    msl[j] = pMax[m * NSLOT + lane + j * 64];
    ssl[j] = pSum[m * NSLOT + lane + j * 64];
    M = fmaxf(M, msl[j]);
  }
  for (int s = 1; s < 64; s <<= 1) M = fmaxf(M, __shfl_xor(M, s));
  float S = 0.f;
#pragma unroll
  for (int j = 0; j < 8; j++) S += ssl[j] * __expf(msl[j] - M);
  for (int s = 1; s < 64; s <<= 1) S += __shfl_xor(S, s);
  const float lse = M + logf(S);

  const int n = m & (N_SEQ - 1);
  float ce = 0.f;
  if (n < N_SEQ - 1) ce = lse - gout[m * (K_TOP + 1) + K_TOP];

  const float g = gout[m * (K_TOP + 1) + lane];
  float gM = g;
  for (int s = 1; s < 64; s <<= 1) gM = fmaxf(gM, __shfl_xor(gM, s));
  float gE = __expf(g - gM);
  float gS = gE;
  for (int s = 1; s < 64; s <<= 1) gS += __shfl_xor(gS, s);
  const float lseK = gM + logf(gS);

  const float tl = t_lp[m * K_TOP + lane];
  const int mk = t_mask[m * K_TOP + lane];
  float kd = mk ? __expf(tl) * (tl - (g - lseK)) : 0.f;
  for (int s = 1; s < 64; s <<= 1) kd += __shfl_xor(kd, s);

  if (lane == 0) atomicAdd(out, 0.5f * kd + 0.5f * ce);
}

// ---------- launch ----------
extern "C" void kernel_launch(void* const* d_in, const int* in_sizes, int n_in,
                              void* d_out, int out_size, void* d_ws, size_t ws_size,
                              hipStream_t stream) {
  const float* x   = (const float*)d_in[0];   // [2,2048,2048]
  const float* Wm  = (const float*)d_in[1];   // [32768,2048]
  const int* tids  = (const int*)d_in[2];     // [2,2048,64]
  const float* tlp = (const float*)d_in[3];   // [2,2048,64]
  const int* tmask = (const int*)d_in[4];     // [2,2048,64]
  const int* tlab  = (const int*)d_in[5];     // [2,2048]
  float* out = (float*)d_out;

  char* ws = (char*)d_ws;
  unsigned char* w8 = (unsigned char*)ws;                                  // 64 MB
  unsigned char* x8 = (unsigned char*)(ws + (size_t)V_DIM * D_DIM);        // 8 MB
  char* p = ws + (size_t)V_DIM * D_DIM + (size_t)M_DIM * D_DIM;
  float* pMax = (float*)p;                       p += (size_t)M_DIM * NSLOT * 4;
  float* pSum = (float*)p;                       p += (size_t)M_DIM * NSLOT * 4;
  float* gout = (float*)p;                       p += (size_t)M_DIM * (K_TOP + 1) * 4;
  unsigned int* bcnt = (unsigned int*)p;         p += 2048 * 4;
  unsigned int* ebuf = (unsigned int*)p;         p += (size_t)2048 * EBCAP * 4;

  hipMemsetAsync(d_out, 0, sizeof(float), stream);
  hipMemsetAsync(bcnt, 0, 2048 * 4, stream);

  bin_kernel<<<(M_DIM * (K_TOP + 1) + 255) / 256, 256, 0, stream>>>(
      tids, tlab, bcnt, ebuf);

  cast_fp8_kernel<<<8192, 256, 0, stream>>>(
      (const float4*)Wm, (uint2*)w8, (V_DIM * D_DIM) / 8,
      (const float4*)x, (uint2*)x8, (M_DIM * D_DIM) / 8);

  gemm_lse_kernel<<<(M_DIM / 256) * (V_DIM / 256), 512, 0, stream>>>(
      x8, w8, pMax, pSum, bcnt, ebuf, gout);

  reduce_kernel<<<M_DIM / 4, 256, 0, stream>>>(pMax, pSum, gout, tlp, tmask, out);
}

// Round 11
// 552.237 us; speedup vs baseline: 1.5252x; 1.0326x over previous
//
#include <hip/hip_runtime.h>
#include <hip/hip_bf16.h>
#include <stdint.h>

typedef __attribute__((ext_vector_type(4))) float f32x4;
typedef __attribute__((ext_vector_type(2))) long l8x16;   // 16 fp8 bytes (2 MFMA ops)

#define D_DIM 2048
#define V_DIM 32768
#define M_DIM 4096
#define N_SEQ 2048
#define K_TOP 64
#define NSLOT 512   // 128 v-tiles * 4 wc
#define EBCAP 512   // entries per 256x256 tile (avg ~130)
#define WSCALE 64.0f
#define IWSCALE 0.015625f

// ---------- helpers ----------
static __device__ __forceinline__ unsigned int f32_to_e4m3(float x) {
  float ax = fminf(fabsf(x), 448.0f);
  unsigned int s = (__float_as_uint(x) >> 31) << 7;
  if (ax >= 0.015625f) {
    unsigned int m = __float_as_uint(ax);
    unsigned int keep = m >> 20;
    unsigned int rb = (m >> 19) & 1u, st = (m & 0x7FFFFu) != 0u;
    keep += rb & (st | (keep & 1u));
    int v = (int)keep - (120 << 3);
    if (v > 0x7E) v = 0x7E;
    return s | (unsigned int)v;
  } else {
    int m = __float2int_rn(ax * 512.0f);
    return s | (unsigned int)m;
  }
}

typedef __attribute__((address_space(3))) unsigned int lds_u32_t;
typedef const __attribute__((address_space(1))) unsigned int glb_u32_t;
static __device__ __forceinline__ void gload16(const void* g, void* l) {
  __builtin_amdgcn_global_load_lds((glb_u32_t*)g, (lds_u32_t*)l, 16, 0, 0);
}

// ---------- cast f32 -> fp8 e4m3, PACKED layout ----------
// Packed 64-B k-block: position q*16 holds [k 8q..8q+8) ++ [k 32+8q..+8).
// Chunk c (= 8 consecutive k) -> uint2 index (c&3)*2 + (c>>2) within block.
__global__ void cast_fp8_kernel(const float4* __restrict__ inA, uint2* __restrict__ outA, int nA8,
                                const float4* __restrict__ inB, uint2* __restrict__ outB, int nB8) {
  int i = blockIdx.x * blockDim.x + threadIdx.x;
  int stride = gridDim.x * blockDim.x;
  int tot = nA8 + nB8;
  for (; i < tot; i += stride) {
    const float4* in = (i < nA8) ? inA : inB;
    uint2* out = (i < nA8) ? outA : outB;
    float sc = (i < nA8) ? WSCALE : 1.0f;
    int j = (i < nA8) ? i : i - nA8;
    float4 a = in[2 * j], b = in[2 * j + 1];
    uint2 r;
    r.x = f32_to_e4m3(a.x * sc) | (f32_to_e4m3(a.y * sc) << 8) |
          (f32_to_e4m3(a.z * sc) << 16) | (f32_to_e4m3(a.w * sc) << 24);
    r.y = f32_to_e4m3(b.x * sc) | (f32_to_e4m3(b.y * sc) << 8) |
          (f32_to_e4m3(b.z * sc) << 16) | (f32_to_e4m3(b.w * sc) << 24);
    int oj = ((j >> 3) << 3) + ((j & 3) << 1) + ((j >> 2) & 1);
    out[oj] = r;
  }
}

// ---------- binning: (m, id) -> per-(mt,vt)-tile entry lists ----------
__global__ __launch_bounds__(256) void bin_kernel(
    const int* __restrict__ tids, const int* __restrict__ tlab,
    unsigned int* __restrict__ cnt, unsigned int* __restrict__ ebuf) {
  int idx = blockIdx.x * 256 + threadIdx.x;
  if (idx >= M_DIM * (K_TOP + 1)) return;
  int m = idx / (K_TOP + 1), k = idx - m * (K_TOP + 1);
  int id;
  if (k < K_TOP) id = tids[m * K_TOP + k];
  else {
    int n = m & (N_SEQ - 1);
    if (n == N_SEQ - 1) return;   // no gold for last position
    id = tlab[m + 1];
  }
  int tile = ((m >> 8) << 7) + (id >> 8);   // mt*128 + vt
  unsigned int pos = atomicAdd(&cnt[tile], 1u);
  if (pos < EBCAP)
    ebuf[tile * EBCAP + pos] =
        ((unsigned int)k << 16) | ((unsigned int)(m & 255) << 8) | (unsigned int)(id & 255);
}

// ---------- 256x256 GEMM, fp8 16x16x32 MFMA, b128 frag reads ----------
// 8 waves (2M x 4N), BK=64 (64 B/row fp8 packed), 64KB LDS dbuf (8KB halves:
// pos0/1 = B rows 0-127/128-255, pos2/3 = A). One b128 read per row per tile:
// granule position p = kqg ^ ((R>>1)&3) (inverse pre-applied on global src);
// per 16-lane group each quad hit exactly 2x = 2-way = free (r5-verified geometry).
// acc descaled x1/64 in epilogues (W pre-scaled x64 into fp8).

#define BAR do { __builtin_amdgcn_s_barrier(); asm volatile("" ::: "memory"); } while (0)
#define VMC(N) asm volatile("s_waitcnt vmcnt(" #N ")" ::: "memory")
#define PRIO1 __builtin_amdgcn_s_setprio(1)
#define PRIO0 __builtin_amdgcn_s_setprio(0)

#define LDF(BASE, R) \
  (*(const l8x16*)((BASE) + (R) * 64 + ((kqg ^ (((R) >> 1) & 3)) << 4)))
#define LDAF(BASE, MI) LDF(BASE, (MI) * 16 + fr)
#define LDBF(BASE, NI) LDF(BASE, brow + (NI) * 16 + fr)

#define STAGE(H) do { \
  int tt_ = (H) >> 2, pos_ = (H) & 3; \
  char* dst_ = ldst + ((tt_ & 1) << 15) + (pos_ << 13); \
  const unsigned char* src_ = ((pos_ & 2) ? aptr : bptr) \
      + ((pos_ & 1) ? (size_t)128 * D_DIM : (size_t)0) + (size_t)tt_ * 64; \
  gload16(src_, dst_); \
} while (0)

// dependent acc reuse distance = 8 MFMAs (ks0 sweep then ks1 sweep)
#define MFMA_Q(M0, U0, U1) do { \
  _Pragma("unroll") \
  for (int ni = 0; ni < 4; ++ni) \
    acc[M0][ni] = __builtin_amdgcn_mfma_f32_16x16x32_fp8_fp8((U0)[0], bF[ni][0], acc[M0][ni], 0, 0, 0); \
  _Pragma("unroll") \
  for (int ni = 0; ni < 4; ++ni) \
    acc[(M0) + 1][ni] = __builtin_amdgcn_mfma_f32_16x16x32_fp8_fp8((U1)[0], bF[ni][0], acc[(M0) + 1][ni], 0, 0, 0); \
  _Pragma("unroll") \
  for (int ni = 0; ni < 4; ++ni) \
    acc[M0][ni] = __builtin_amdgcn_mfma_f32_16x16x32_fp8_fp8((U0)[1], bF[ni][1], acc[M0][ni], 0, 0, 0); \
  _Pragma("unroll") \
  for (int ni = 0; ni < 4; ++ni) \
    acc[(M0) + 1][ni] = __builtin_amdgcn_mfma_f32_16x16x32_fp8_fp8((U1)[1], bF[ni][1], acc[(M0) + 1][ni], 0, 0, 0); \
} while (0)

// Entering invariant: bF = B(T), a01 = A mi0,1 of T (read in s4 of T-1 / prologue).
#define TILE1B(T, DOST, NVM, DONEXT) do { \
  char* curA_ = ldsAroot + (((T) & 1) << 15); \
  char* nxtA_ = ldsAroot + ((((T) + 1) & 1) << 15); \
  char* nxtB_ = ldsBroot + ((((T) + 1) & 1) << 15); \
  /* s1 */ \
  BAR; \
  if (DOST) STAGE(4 * (T) + 8); \
  PRIO1; MFMA_Q(0, a01[0], a01[1]); PRIO0; \
  a23[0] = LDAF(curA_, 2); a23[1] = LDAF(curA_, 3); \
  /* s2 */ \
  BAR; \
  if (DOST) STAGE(4 * (T) + 9); \
  PRIO1; MFMA_Q(2, a23[0], a23[1]); PRIO0; \
  a45[0] = LDAF(curA_, 4); a45[1] = LDAF(curA_, 5); \
  /* s3 */ \
  BAR; \
  PRIO1; MFMA_Q(4, a45[0], a45[1]); PRIO0; \
  a67[0] = LDAF(curA_, 6); a67[1] = LDAF(curA_, 7); \
  if ((NVM) == 2) { VMC(2); } else if ((NVM) == 0) { VMC(0); } \
  /* s4 */ \
  BAR; \
  if (DOST) { STAGE(4 * (T) + 10); STAGE(4 * (T) + 11); } \
  PRIO1; MFMA_Q(6, a67[0], a67[1]); PRIO0; \
  if (DONEXT) { \
    bF[0] = LDBF(nxtB_, 0); bF[1] = LDBF(nxtB_, 1); \
    bF[2] = LDBF(nxtB_, 2); bF[3] = LDBF(nxtB_, 3); \
    a01[0] = LDAF(nxtA_, 0); a01[1] = LDAF(nxtA_, 1); \
  } \
} while (0)

__global__ __launch_bounds__(512, 2) void gemm_lse_kernel(
    const unsigned char* __restrict__ x8,     // [M_DIM][D_DIM] fp8 packed
    const unsigned char* __restrict__ w8,     // [V_DIM][D_DIM] fp8 packed (x64)
    float* __restrict__ pMax,                 // [M_DIM][NSLOT]
    float* __restrict__ pSum,
    const unsigned int* __restrict__ bcnt,    // [2048]
    const unsigned int* __restrict__ ebuf,    // [2048][EBCAP]
    float* __restrict__ gout) {               // [M_DIM][K_TOP+1]
  __shared__ __align__(16) char lds[131072];  // GEMM uses first 64KB; epilogue all

  // Locality mapping (round-5): round of 256 blocks = 16mt x 16vt square;
  // each XCD pinned to 2 vt columns.
  const int bid0 = blockIdx.x;
  const int mt = (bid0 >> 4) & 15;
  const int vt = ((bid0 >> 8) << 4) | (bid0 & 15);
  const int tid = threadIdx.x, lane = tid & 63, w = tid >> 6;
  const int wr = w >> 2, wc = w & 3;
  const int fr = lane & 15, kqg = lane >> 4;
  const int brow = (wc & 1) * 64;

  // staging: thread t -> row t>>2, granule pos t&3; src pos pre-swizzled
  const int gcol = (((tid & 3) ^ ((tid >> 3) & 3)) << 4);
  const unsigned char* aptr = x8 + (size_t)(mt * 256 + (tid >> 2)) * D_DIM + gcol;
  const unsigned char* bptr = w8 + (size_t)(vt * 256 + (tid >> 2)) * D_DIM + gcol;
  char* ldst = lds + tid * 16;

  char* ldsAroot = lds + ((2 + wr) << 13);
  char* ldsBroot = lds + ((wc >> 1) << 13);

  f32x4 acc[8][4];
#pragma unroll
  for (int i = 0; i < 8; i++)
#pragma unroll
    for (int j = 0; j < 4; j++) acc[i][j] = (f32x4){0.f, 0.f, 0.f, 0.f};

  l8x16 bF[4], a01[2], a23[2], a45[2], a67[2];

  // prologue: stage tiles 0 and 1 fully (halves 0..7), drain, pre-read tile0
  STAGE(0); STAGE(1); STAGE(2); STAGE(3);
  STAGE(4); STAGE(5); STAGE(6); STAGE(7);
  VMC(0);
  BAR;
  bF[0] = LDBF(ldsBroot, 0); bF[1] = LDBF(ldsBroot, 1);
  bF[2] = LDBF(ldsBroot, 2); bF[3] = LDBF(ldsBroot, 3);
  a01[0] = LDAF(ldsAroot, 0); a01[1] = LDAF(ldsAroot, 1);

  // main loop: tiles 0..29 (stage T+2), tail tiles 30, 31
  for (int it = 0; it < 15; ++it) {
    TILE1B(2 * it, 1, 2, 1);
    TILE1B(2 * it + 1, 1, 2, 1);
  }
  TILE1B(30, 0, 0, 1);
  TILE1B(31, 0, 99, 0);

  // ---- epilogue A: per-row (max, sumexp); descale acc by 1/64 ----
  const int slot = vt * 4 + wc;
#pragma unroll
  for (int mi = 0; mi < 8; mi++) {
#pragma unroll
    for (int j = 0; j < 4; j++) {
      const int row = mt * 256 + wr * 128 + mi * 16 + kqg * 4 + j;
      float v0 = acc[mi][0][j] * IWSCALE, v1 = acc[mi][1][j] * IWSCALE;
      float v2 = acc[mi][2][j] * IWSCALE, v3 = acc[mi][3][j] * IWSCALE;
      float mx = fmaxf(fmaxf(v0, v1), fmaxf(v2, v3));
      for (int s = 1; s < 16; s <<= 1) mx = fmaxf(mx, __shfl_xor(mx, s));
      float sm = __expf(v0 - mx) + __expf(v1 - mx) +
                 __expf(v2 - mx) + __expf(v3 - mx);
      for (int s = 1; s < 16; s <<= 1) sm += __shfl_xor(sm, s);
      if (fr == 0) {
        pMax[row * NSLOT + slot] = mx;
        pSum[row * NSLOT + slot] = sm;
      }
    }
  }

  // ---- epilogue B: fused gather of requested logits via LDS round-trip ----
  const int tile = (mt << 7) + vt;
  unsigned int cn = bcnt[tile];
  if (cn > EBCAP) cn = EBCAP;
  const unsigned int* elist = ebuf + tile * EBCAP;
  float* ldsf = (float*)lds;

  __syncthreads();
#pragma unroll
  for (int half = 0; half < 2; ++half) {
    if (wr == half) {
#pragma unroll
      for (int mi = 0; mi < 8; mi++) {
        const int r0 = mi * 16 + kqg * 4;
        const int cs = (kqg & 1) << 4;
#pragma unroll
        for (int ni = 0; ni < 4; ni++) {
          const int c0 = (wc * 64 + ni * 16 + fr) ^ cs;
#pragma unroll
          for (int j = 0; j < 4; j++)
            ldsf[(r0 + j) * 256 + c0] = acc[mi][ni][j] * IWSCALE;
        }
      }
    }
    __syncthreads();
    for (unsigned int e = tid; e < cn; e += 512) {
      unsigned int u = elist[e];
      int r = (u >> 8) & 255;
      if ((r >> 7) == half) {
        int c = u & 255, k = u >> 16;
        int rl = r & 127;
        gout[(mt * 256 + r) * (K_TOP + 1) + k] = ldsf[rl * 256 + (c ^ (((rl >> 2) & 1) << 4))];
      }
    }
    __syncthreads();
  }
}

// ---------- final: lse merge + CE + KD, atomic into scalar ----------
__global__ __launch_bounds__(256) void reduce_kernel(
    const float* __restrict__ pMax, const float* __restrict__ pSum,
    const float* __restrict__ gout, const float* __restrict__ t_lp,
    const int* __restrict__ t_mask, float* __restrict__ out) {
  const int tid = threadIdx.x, lane = tid & 63, w = tid >> 6;
  const int m = blockIdx.x * 4 + w;

  float msl[8], ssl[8];
  float M = -1e30f;
#pragma unroll
  for (int j = 0; j < 8; j++) {
    msl[j] = pMax[m * NSLOT + lane + j * 64];
    ssl[j] = pSum[m * NSLOT + lane + j * 64];
    M = fmaxf(M, msl[j]);
  }
  for (int s = 1; s < 64; s <<= 1) M = fmaxf(M, __shfl_xor(M, s));
  float S = 0.f;
#pragma unroll
  for (int j = 0; j < 8; j++) S += ssl[j] * __expf(msl[j] - M);
  for (int s = 1; s < 64; s <<= 1) S += __shfl_xor(S, s);
  const float lse = M + logf(S);

  const int n = m & (N_SEQ - 1);
  float ce = 0.f;
  if (n < N_SEQ - 1) ce = lse - gout[m * (K_TOP + 1) + K_TOP];

  const float g = gout[m * (K_TOP + 1) + lane];
  float gM = g;
  for (int s = 1; s < 64; s <<= 1) gM = fmaxf(gM, __shfl_xor(gM, s));
  float gE = __expf(g - gM);
  float gS = gE;
  for (int s = 1; s < 64; s <<= 1) gS += __shfl_xor(gS, s);
  const float lseK = gM + logf(gS);

  const float tl = t_lp[m * K_TOP + lane];
  const int mk = t_mask[m * K_TOP + lane];
  float kd = mk ? __expf(tl) * (tl - (g - lseK)) : 0.f;
  for (int s = 1; s < 64; s <<= 1) kd += __shfl_xor(kd, s);

  if (lane == 0) atomicAdd(out, 0.5f * kd + 0.5f * ce);
}

// ---------- launch ----------
extern "C" void kernel_launch(void* const* d_in, const int* in_sizes, int n_in,
                              void* d_out, int out_size, void* d_ws, size_t ws_size,
                              hipStream_t stream) {
  const float* x   = (const float*)d_in[0];   // [2,2048,2048]
  const float* Wm  = (const float*)d_in[1];   // [32768,2048]
  const int* tids  = (const int*)d_in[2];     // [2,2048,64]
  const float* tlp = (const float*)d_in[3];   // [2,2048,64]
  const int* tmask = (const int*)d_in[4];     // [2,2048,64]
  const int* tlab  = (const int*)d_in[5];     // [2,2048]
  float* out = (float*)d_out;

  char* ws = (char*)d_ws;
  unsigned char* w8 = (unsigned char*)ws;                                  // 64 MB
  unsigned char* x8 = (unsigned char*)(ws + (size_t)V_DIM * D_DIM);        // 8 MB
  char* p = ws + (size_t)V_DIM * D_DIM + (size_t)M_DIM * D_DIM;
  float* pMax = (float*)p;                       p += (size_t)M_DIM * NSLOT * 4;
  float* pSum = (float*)p;                       p += (size_t)M_DIM * NSLOT * 4;
  float* gout = (float*)p;                       p += (size_t)M_DIM * (K_TOP + 1) * 4;
  unsigned int* bcnt = (unsigned int*)p;         p += 2048 * 4;
  unsigned int* ebuf = (unsigned int*)p;         p += (size_t)2048 * EBCAP * 4;

  hipMemsetAsync(d_out, 0, sizeof(float), stream);
  hipMemsetAsync(bcnt, 0, 2048 * 4, stream);

  bin_kernel<<<(M_DIM * (K_TOP + 1) + 255) / 256, 256, 0, stream>>>(
      tids, tlab, bcnt, ebuf);

  cast_fp8_kernel<<<8192, 256, 0, stream>>>(
      (const float4*)Wm, (uint2*)w8, (V_DIM * D_DIM) / 8,
      (const float4*)x, (uint2*)x8, (M_DIM * D_DIM) / 8);

  gemm_lse_kernel<<<(M_DIM / 256) * (V_DIM / 256), 512, 0, stream>>>(
      x8, w8, pMax, pSum, bcnt, ebuf, gout);

  reduce_kernel<<<M_DIM / 4, 256, 0, stream>>>(pMax, pSum, gout, tlp, tmask, out);
}